// Round 8
// baseline (486.095 us; speedup 1.0000x reference)
//
#include <hip/hip_runtime.h>
#include <hip/hip_bf16.h>
#include <hip/hip_fp16.h>

#define N 8192
#define FIN 256
#define HD 256
#define LEAKY 0.2f

typedef short sh8 __attribute__((ext_vector_type(8)));       // bf16x8 MFMA fragment
typedef _Float16 h8 __attribute__((ext_vector_type(8)));     // f16x8 MFMA fragment
typedef _Float16 h2 __attribute__((ext_vector_type(2)));
typedef float f32x4 __attribute__((ext_vector_type(4)));
typedef int   i32x4 __attribute__((ext_vector_type(4)));

__device__ __forceinline__ int pack2bf(float a, float b){
  __hip_bfloat162 t = __float22bfloat162_rn(make_float2(a, b));
  union { __hip_bfloat162 h; int i; } u;
  u.h = t;
  return u.i;
}

__device__ __forceinline__ h2 u2h2(unsigned u){ union{unsigned u; h2 h;} c; c.u=u; return c.h; }
__device__ __forceinline__ unsigned h22u(h2 h){ union{unsigned u; h2 h;} c; c.h=h; return c.u; }

// ---------------- K0: W (256x256 f32, [k][c]) -> Wt (bf16, [c][k]) ----------------
__global__ void k_wt(const float* __restrict__ W, __hip_bfloat16* __restrict__ Wt){
  __shared__ float t[16][17];
  int tx = threadIdx.x, ty = threadIdx.y;
  int bx = blockIdx.x*16, by = blockIdx.y*16;
  t[ty][tx] = W[(by+ty)*HD + (bx+tx)];
  __syncthreads();
  Wt[(bx+ty)*FIN + (by+tx)] = __float2bfloat16(t[tx][ty]);
}

// ---------------- K1: h_t[c][n] (f16) + El/El2 fp32 + Erh/Er2h f16 ------------------
__global__ __launch_bounds__(256, 2) void k_h(
    const float* __restrict__ x, const __hip_bfloat16* __restrict__ Wt,
    const float* __restrict__ a_l, const float* __restrict__ a_r,
    _Float16* __restrict__ ht, float* __restrict__ El, float* __restrict__ El2,
    _Float16* __restrict__ Erh, _Float16* __restrict__ Er2h)
{
  const int lane = threadIdx.x & 63;
  const int w = threadIdx.x >> 6;      // c-group == head
  const int r0 = lane & 15, q = lane >> 4;
  const int c0 = w*64;
  const int n0 = blockIdx.x*32;

  f32x4 acc[4][2];
  #pragma unroll
  for (int m = 0; m < 4; ++m)
    #pragma unroll
    for (int nt = 0; nt < 2; ++nt)
      acc[m][nt] = (f32x4){0.f, 0.f, 0.f, 0.f};

  for (int kb = 0; kb < 8; ++kb){
    const int k = kb*32 + q*8;
    sh8 af[4];
    #pragma unroll
    for (int m = 0; m < 4; ++m)
      af[m] = *(const sh8*)(Wt + (c0 + m*16 + r0)*FIN + k);
    #pragma unroll
    for (int nt = 0; nt < 2; ++nt){
      const float* xp = x + (n0 + nt*16 + r0)*FIN + k;
      f32x4 xl = *(const f32x4*)xp;
      f32x4 xh = *(const f32x4*)(xp + 4);
      union { sh8 s; int i[4]; } bx;
      bx.i[0] = pack2bf(xl[0], xl[1]);
      bx.i[1] = pack2bf(xl[2], xl[3]);
      bx.i[2] = pack2bf(xh[0], xh[1]);
      bx.i[3] = pack2bf(xh[2], xh[3]);
      #pragma unroll
      for (int m = 0; m < 4; ++m)
        acc[m][nt] = __builtin_amdgcn_mfma_f32_16x16x32_bf16(af[m], bx.s, acc[m][nt], 0, 0, 0);
    }
  }

  float pl[2] = {0.f, 0.f}, pr[2] = {0.f, 0.f};
  #pragma unroll
  for (int m = 0; m < 4; ++m){
    #pragma unroll
    for (int reg = 0; reg < 4; ++reg){
      const int c = c0 + m*16 + q*4 + reg;      // C row = q*4+reg
      const float alv = a_l[c], arv = a_r[c];
      #pragma unroll
      for (int nt = 0; nt < 2; ++nt){
        float v = acc[m][nt][reg];
        ht[(size_t)c*N + (n0 + nt*16 + r0)] = (_Float16)v;  // C col = r0
        pl[nt] += v*alv;
        pr[nt] += v*arv;
      }
    }
  }
  #pragma unroll
  for (int nt = 0; nt < 2; ++nt){
    pl[nt] += __shfl_xor(pl[nt], 16); pl[nt] += __shfl_xor(pl[nt], 32);
    pr[nt] += __shfl_xor(pr[nt], 16); pr[nt] += __shfl_xor(pr[nt], 32);
  }
  if (lane < 16){
    #pragma unroll
    for (int nt = 0; nt < 2; ++nt){
      const int n = n0 + nt*16 + r0;
      const float l = pl[nt], r = pr[nt];
      El  [w*N + n] = __expf(l);
      El2 [w*N + n] = __expf(LEAKY*l);
      Erh [w*N + n] = (_Float16)__expf(r);
      Er2h[w*N + n] = (_Float16)__expf(LEAKY*r);
    }
  }
}

// ---------------- K_bits: adj (N*N int32) -> bitmask u64[row][N/64], eye OR'd in ---
__global__ __launch_bounds__(256) void k_bits(const int* __restrict__ adj,
                                              unsigned long long* __restrict__ bits)
{
  const int lane = threadIdx.x & 63;
  const int wid = (blockIdx.x*256 + threadIdx.x) >> 6;   // global wave id
  const int nw = (gridDim.x*256) >> 6;
  const int total = (N/64)*N;                            // row-major: idx = r*128 + c
  for (int idx = wid; idx < total; idx += nw){
    const int r = idx >> 7, c = idx & 127;
    int av = __builtin_nontemporal_load(adj + (size_t)r*N + c*64 + lane);
    unsigned long long b = __ballot(av != 0);
    if (c == (r >> 6)) b |= 1ull << (r & 63);            // + eye
    if (lane == 0) bits[idx] = b;
  }
}

// ---------------- K2: masked-softmax numerator/denominator partials ----------------
// grid 1024: b -> head (b&3), j-quarter ((b>>2)&3), i-range 128 rows (b>>4).
// 4 waves, ALL same head; wave w owns rows i128*128 + w*32 + {0,16} + r0.
// 128-j f16 tile (64 feat x 128 j = 16 KB) double-buffered in LDS; one barrier/tile.
// vmcnt-FIFO discipline: ALL body-consumed vmem (bits, er) is issued BEFORE the
// staging global_load_lds ops (pinned by sched_barrier), so consuming er/bits
// needs only vmcnt(4) and never drains the in-flight staging of the next tile.
__device__ __forceinline__ void sub_compute(
    const char* frp, int loff, i32x4 er4, i32x4 er24,
    unsigned sw0, unsigned sw1, const h2 elh[2], const h2 el2h[2], int q,
    const h8& ones, f32x4 acc[2][4], f32x4 accz[2])
{
  h8 hf[4];
  #pragma unroll
  for (int d = 0; d < 4; ++d)
    hf[d] = *(const h8*)(frp + loff + d*1024);         // ds_read_b128

  #pragma unroll
  for (int m = 0; m < 2; ++m){
    const unsigned sw = ((m == 0) ? sw0 : sw1) >> (q*8);
    unsigned fu[4];
    #pragma unroll
    for (int p = 0; p < 4; ++p){
      h2 w2 = __builtin_elementwise_max(elh[m]  * u2h2((unsigned)er4[p]),
                                        el2h[m] * u2h2((unsigned)er24[p]));
      unsigned wu = h22u(w2);
      const unsigned t = sw >> (2*p);
      wu = (t & 1u) ? wu : (wu & 0xFFFF0000u);         // zero low (j=2p) if masked
      wu = (t & 2u) ? wu : (wu & 0x0000FFFFu);         // zero high (j=2p+1) if masked
      fu[p] = wu;
    }
    union { h8 s; unsigned u[4]; } fa;
    fa.u[0]=fu[0]; fa.u[1]=fu[1]; fa.u[2]=fu[2]; fa.u[3]=fu[3];
    #pragma unroll
    for (int d = 0; d < 4; ++d)
      acc[m][d] = __builtin_amdgcn_mfma_f32_16x16x32_f16(fa.s, hf[d], acc[m][d], 0, 0, 0);
    accz[m] = __builtin_amdgcn_mfma_f32_16x16x32_f16(fa.s, ones, accz[m], 0, 0, 0);
  }
}

__global__ __launch_bounds__(256, 4) void k_attn(
    const unsigned* __restrict__ bits32, const _Float16* __restrict__ ht,
    const float* __restrict__ El, const float* __restrict__ El2,
    const _Float16* __restrict__ Erh, const _Float16* __restrict__ Er2h,
    float* __restrict__ part, float* __restrict__ zpart)
{
  __shared__ __align__(16) char smem[32768];    // 2 x 16 KB tile buffers
  const int b = blockIdx.x;
  const int h = b & 3, jq = (b >> 2) & 3, i128 = b >> 4;
  const int tid = threadIdx.x;
  const int lane = tid & 63;
  const int w = tid >> 6;
  const int r0 = lane & 15, q = lane >> 4;
  const int ib = i128*128 + w*32;               // this wave's 32-row base
  const int jbase = jq * 2048;

  // staging: thread -> feat f = w*16+(lane>>2); LDS slot (lane&3) gets global
  // j-chunk (lane&3)^((lane>>3)&3).  LDS dest = s*4096 + w*1024 + lane*16.
  const _Float16* gp = ht + (size_t)(h*64 + w*16 + (lane >> 2))*N
                          + jbase + (((lane & 3) ^ ((lane >> 3) & 3))*8);
  char* lb = smem + w*1024;

  // fragment read: (f = d*16+r0), slot q ^ ((r0>>1)&3)  -> global chunk q
  const char* frp = smem + r0*64 + ((q ^ ((r0 >> 1) & 3)) << 4);

  const float* el_ = El  + h*N + ib + r0;
  const float* el2_= El2 + h*N + ib + r0;
  h2 elh[2], el2h[2];
  #pragma unroll
  for (int m = 0; m < 2; ++m){
    _Float16 a = (_Float16)el_[m*16];
    _Float16 c = (_Float16)el2_[m*16];
    elh[m]  = (h2){a, a};
    el2h[m] = (h2){c, c};
  }
  const unsigned* bp0 = bits32 + (size_t)(ib + r0)*(N/32) + (jbase >> 5);
  const unsigned* bp1 = bp0 + 16*(N/32);
  const _Float16* erq  = Erh  + h*N + jbase + q*8;
  const _Float16* er2q = Er2h + h*N + jbase + q*8;

  union { h8 s; int i[4]; } onef;
  {
    int v = (r0 == 0) ? 0x3C003C00 : 0;          // f16 1.0 pair
    onef.i[0]=v; onef.i[1]=v; onef.i[2]=v; onef.i[3]=v;
  }

  f32x4 acc[2][4];
  f32x4 accz[2];
  #pragma unroll
  for (int m = 0; m < 2; ++m){
    accz[m] = (f32x4){0.f,0.f,0.f,0.f};
    #pragma unroll
    for (int d = 0; d < 4; ++d)
      acc[m][d] = (f32x4){0.f,0.f,0.f,0.f};
  }

#define STAGE(bufoff, t) do { \
    const _Float16* _g = gp + (t)*128; \
    _Pragma("unroll") \
    for (int _s = 0; _s < 4; ++_s) \
      __builtin_amdgcn_global_load_lds( \
        (const __attribute__((address_space(1))) void*)(_g + _s*32), \
        (__attribute__((address_space(3))) void*)(lb + (bufoff) + _s*4096), 16, 0, 0); \
  } while(0)

  STAGE(0, 0);
  __syncthreads();                               // tile 0 resident in buf0

  for (int t = 0; t < 16; ++t){
    const int bo = (t & 1) ? 16384 : 0;
    const int bn = bo ^ 16384;
    const int tn = (t + 1) & 15;                 // tail wrap harmless

    // --- body-consumed vmem FIRST: older than staging in the vmcnt FIFO ---
    i32x4 bw0 = *(const i32x4*)(bp0 + t*4);
    i32x4 bw1 = *(const i32x4*)(bp1 + t*4);
    i32x4 er4a[4], er24a[4];
    #pragma unroll
    for (int ss = 0; ss < 4; ++ss){
      er4a[ss]  = *(const i32x4*)(erq  + t*128 + ss*32);
      er24a[ss] = *(const i32x4*)(er2q + t*128 + ss*32);
    }
    __builtin_amdgcn_sched_barrier(0);           // pin: er/bits issue before STAGE
    STAGE(bn, tn);                               // async: next tile -> other buffer

    #pragma unroll
    for (int ss = 0; ss < 4; ++ss)
      sub_compute(frp, bo + ss*4096, er4a[ss], er24a[ss],
                  (unsigned)bw0[ss], (unsigned)bw1[ss],
                  elh, el2h, q, onef.s, acc, accz);

    __syncthreads();                             // next tile staged; this buf free
  }

  // z partials: col 0 of accz -> lanes with r0==0, row = q*4+reg
  if (r0 == 0){
    #pragma unroll
    for (int m = 0; m < 2; ++m)
      #pragma unroll
      for (int reg = 0; reg < 4; ++reg)
        zpart[(jq*4 + h)*N + ib + m*16 + q*4 + reg] = accz[m][reg];
  }

  // numerator partials: C layout col=r0, row=q*4+reg
  float* pp = part + (size_t)jq*N*HD + h*64 + r0;
  #pragma unroll
  for (int m = 0; m < 2; ++m)
    #pragma unroll
    for (int d = 0; d < 4; ++d)
      #pragma unroll
      for (int reg = 0; reg < 4; ++reg)
        pp[(size_t)(ib + m*16 + q*4 + reg)*HD + d*16] = acc[m][d][reg];
#undef STAGE
}

// ---------------- K3: combine 4 j-quarter partials, divide, write out --------------
__global__ void k_out(const float* __restrict__ part, const float* __restrict__ zpart,
                      float* __restrict__ out)
{
  const int t4 = (blockIdx.x*256 + threadIdx.x) * 4;   // 4 consecutive c (same head)
  const int i = t4 >> 8;
  const int h = (t4 & 255) >> 6;
  f32x4 a = *(const f32x4*)(part + t4);
  f32x4 bq = *(const f32x4*)(part + (size_t)N*HD + t4);
  f32x4 c = *(const f32x4*)(part + 2*(size_t)N*HD + t4);
  f32x4 d = *(const f32x4*)(part + 3*(size_t)N*HD + t4);
  float zz = zpart[h*N + i] + zpart[(4 + h)*N + i] + zpart[(8 + h)*N + i] + zpart[(12 + h)*N + i];
  f32x4 s = (a + bq + c + d) / zz;
  *(f32x4*)(out + t4) = s;
}

extern "C" void kernel_launch(void* const* d_in, const int* in_sizes, int n_in,
                              void* d_out, int out_size, void* d_ws, size_t ws_size,
                              hipStream_t stream) {
  const float* x   = (const float*)d_in[0];
  const int*   adj = (const int*)d_in[1];
  const float* W   = (const float*)d_in[2];
  const float* a_l = (const float*)d_in[3];
  const float* a_r = (const float*)d_in[4];
  float* out = (float*)d_out;

  char* ws = (char*)d_ws;
  __hip_bfloat16* Wt = (__hip_bfloat16*)ws;                     // 128 KB
  _Float16* ht   = (_Float16*)(ws + 131072);                    // 4 MB
  float*    El   = (float*)   (ws + 4325376);                   // 128 KB
  float*    El2  = (float*)   (ws + 4456448);                   // 128 KB
  _Float16* Erh  = (_Float16*)(ws + 4587520);                   // 64 KB
  _Float16* Er2h = (_Float16*)(ws + 4653056);                   // 64 KB
  unsigned long long* bits = (unsigned long long*)(ws + 4718592); // 8 MB
  float*    part = (float*)   (ws + 13107200);                  // 32 MB
  float*    zpart= (float*)   (ws + 46661632);                  // 512 KB

  k_wt  <<<dim3(16,16), dim3(16,16), 0, stream>>>(W, Wt);
  k_h   <<<256, 256, 0, stream>>>(x, Wt, a_l, a_r, ht, El, El2, Erh, Er2h);
  k_bits<<<4096, 256, 0, stream>>>(adj, bits);
  k_attn<<<1024, 256, 0, stream>>>((const unsigned*)bits, ht, El, El2, Erh, Er2h, part, zpart);
  k_out <<<N*HD/1024, 256, 0, stream>>>(part, zpart, out);
}

// Round 9
// 477.294 us; speedup vs baseline: 1.0184x; 1.0184x over previous
//
#include <hip/hip_runtime.h>
#include <hip/hip_bf16.h>
#include <hip/hip_fp16.h>

#define N 8192
#define FIN 256
#define HD 256
#define LEAKY 0.2f

typedef short sh8 __attribute__((ext_vector_type(8)));       // bf16x8 MFMA fragment
typedef _Float16 h8 __attribute__((ext_vector_type(8)));     // f16x8 MFMA fragment
typedef _Float16 h2 __attribute__((ext_vector_type(2)));
typedef float f32x4 __attribute__((ext_vector_type(4)));
typedef int   i32x4 __attribute__((ext_vector_type(4)));

__device__ __forceinline__ int pack2bf(float a, float b){
  __hip_bfloat162 t = __float22bfloat162_rn(make_float2(a, b));
  union { __hip_bfloat162 h; int i; } u;
  u.h = t;
  return u.i;
}

__device__ __forceinline__ h2 u2h2(unsigned u){ union{unsigned u; h2 h;} c; c.u=u; return c.h; }
__device__ __forceinline__ unsigned h22u(h2 h){ union{unsigned u; h2 h;} c; c.h=h; return c.u; }

// ---------------- K0: W (256x256 f32, [k][c]) -> Wt (bf16, [c][k]) ----------------
__global__ void k_wt(const float* __restrict__ W, __hip_bfloat16* __restrict__ Wt){
  __shared__ float t[16][17];
  int tx = threadIdx.x, ty = threadIdx.y;
  int bx = blockIdx.x*16, by = blockIdx.y*16;
  t[ty][tx] = W[(by+ty)*HD + (bx+tx)];
  __syncthreads();
  Wt[(bx+ty)*FIN + (by+tx)] = __float2bfloat16(t[tx][ty]);
}

// ---------------- K1: h_t[c][n] (f16) + El/El2 fp32 + Erh/Er2h f16 ------------------
__global__ __launch_bounds__(256, 2) void k_h(
    const float* __restrict__ x, const __hip_bfloat16* __restrict__ Wt,
    const float* __restrict__ a_l, const float* __restrict__ a_r,
    _Float16* __restrict__ ht, float* __restrict__ El, float* __restrict__ El2,
    _Float16* __restrict__ Erh, _Float16* __restrict__ Er2h)
{
  const int lane = threadIdx.x & 63;
  const int w = threadIdx.x >> 6;      // c-group == head
  const int r0 = lane & 15, q = lane >> 4;
  const int c0 = w*64;
  const int n0 = blockIdx.x*32;

  f32x4 acc[4][2];
  #pragma unroll
  for (int m = 0; m < 4; ++m)
    #pragma unroll
    for (int nt = 0; nt < 2; ++nt)
      acc[m][nt] = (f32x4){0.f, 0.f, 0.f, 0.f};

  for (int kb = 0; kb < 8; ++kb){
    const int k = kb*32 + q*8;
    sh8 af[4];
    #pragma unroll
    for (int m = 0; m < 4; ++m)
      af[m] = *(const sh8*)(Wt + (c0 + m*16 + r0)*FIN + k);
    #pragma unroll
    for (int nt = 0; nt < 2; ++nt){
      const float* xp = x + (n0 + nt*16 + r0)*FIN + k;
      f32x4 xl = *(const f32x4*)xp;
      f32x4 xh = *(const f32x4*)(xp + 4);
      union { sh8 s; int i[4]; } bx;
      bx.i[0] = pack2bf(xl[0], xl[1]);
      bx.i[1] = pack2bf(xl[2], xl[3]);
      bx.i[2] = pack2bf(xh[0], xh[1]);
      bx.i[3] = pack2bf(xh[2], xh[3]);
      #pragma unroll
      for (int m = 0; m < 4; ++m)
        acc[m][nt] = __builtin_amdgcn_mfma_f32_16x16x32_bf16(af[m], bx.s, acc[m][nt], 0, 0, 0);
    }
  }

  float pl[2] = {0.f, 0.f}, pr[2] = {0.f, 0.f};
  #pragma unroll
  for (int m = 0; m < 4; ++m){
    #pragma unroll
    for (int reg = 0; reg < 4; ++reg){
      const int c = c0 + m*16 + q*4 + reg;      // C row = q*4+reg
      const float alv = a_l[c], arv = a_r[c];
      #pragma unroll
      for (int nt = 0; nt < 2; ++nt){
        float v = acc[m][nt][reg];
        ht[(size_t)c*N + (n0 + nt*16 + r0)] = (_Float16)v;  // C col = r0
        pl[nt] += v*alv;
        pr[nt] += v*arv;
      }
    }
  }
  #pragma unroll
  for (int nt = 0; nt < 2; ++nt){
    pl[nt] += __shfl_xor(pl[nt], 16); pl[nt] += __shfl_xor(pl[nt], 32);
    pr[nt] += __shfl_xor(pr[nt], 16); pr[nt] += __shfl_xor(pr[nt], 32);
  }
  if (lane < 16){
    #pragma unroll
    for (int nt = 0; nt < 2; ++nt){
      const int n = n0 + nt*16 + r0;
      const float l = pl[nt], r = pr[nt];
      El  [w*N + n] = __expf(l);
      El2 [w*N + n] = __expf(LEAKY*l);
      Erh [w*N + n] = (_Float16)__expf(r);
      Er2h[w*N + n] = (_Float16)__expf(LEAKY*r);
    }
  }
}

// ---------------- K2: fused adj-mask + masked-softmax partials ----------------------
// grid 1024: b = h*256 + jq*64 + i128. The 4 same-(jq,i128) blocks (h=0..3) have
// indices 256 apart == same XCD slot -> adj slice shared via L1/L2 (256 MB HBM once).
// 4 waves, same head; wave w owns rows i128*128 + w*32 + {0,16} + r0.
// adj read directly (values are {0,1}); eye handled via precomputed lane flag in the
// single (t,ss) subtile intersecting each wave's rows. ht tile in LDS as round 7.
__global__ __launch_bounds__(256, 4) void k_attn(
    const int* __restrict__ adj, const _Float16* __restrict__ ht,
    const float* __restrict__ El, const float* __restrict__ El2,
    const _Float16* __restrict__ Erh, const _Float16* __restrict__ Er2h,
    float* __restrict__ part, float* __restrict__ zpart)
{
  __shared__ __align__(16) char smem[32768];    // 2 x 16 KB ht tile buffers
  const int b = blockIdx.x;
  const int h = b >> 8, jq = (b >> 6) & 3, i128 = b & 63;
  const int tid = threadIdx.x;
  const int lane = tid & 63;
  const int w = tid >> 6;
  const int r0 = lane & 15, q = lane >> 4;
  const int ib = i128*128 + w*32;               // this wave's 32-row base
  const int jbase = jq * 2048;

  // ht staging (round-7 swizzle): feat f = w*16+(lane>>2); slot (lane&3) holds
  // global j-chunk (lane&3)^((lane>>3)&3). LDS dest = s*4096 + w*1024 + lane*16.
  const _Float16* gp = ht + (size_t)(h*64 + w*16 + (lane >> 2))*N
                          + jbase + (((lane & 3) ^ ((lane >> 3) & 3))*8);
  char* lb = smem + w*1024;
  // fragment read: (f = d*16+r0), slot q ^ ((r0>>1)&3) -> global chunk q
  const char* frp = smem + r0*64 + ((q ^ ((r0 >> 1) & 3)) << 4);

  const float* el_ = El  + h*N + ib + r0;
  const float* el2_= El2 + h*N + ib + r0;
  h2 elh[2], el2h[2];
  #pragma unroll
  for (int m = 0; m < 2; ++m){
    _Float16 a = (_Float16)el_[m*16];
    _Float16 c = (_Float16)el2_[m*16];
    elh[m]  = (h2){a, a};
    el2h[m] = (h2){c, c};
  }
  const _Float16* erq  = Erh  + h*N + jbase + q*8;
  const _Float16* er2q = Er2h + h*N + jbase + q*8;

  // adj pointers: row (ib + m*16 + r0), j base (jbase + q*8)
  const int* ap0 = adj + (size_t)(ib + r0)*N + jbase + q*8;
  const int* ap1 = ap0 + 16*N;

  // diagonal (+eye): for each m, exactly one (t,ss) subtile intersects rows
  int td[2], sd[2], pd[2];
  unsigned eyem[2];
  bool db[2];
  #pragma unroll
  for (int m = 0; m < 2; ++m){
    const int am = ib + m*16;                   // 16-aligned row base
    db[m] = ((am >> 11) == jq);                 // j-quarter contains these rows?
    td[m] = (am >> 7) & 15;
    sd[m] = (am >> 5) & 3;
    const int dr = (am & 31) + r0;              // row - subtile j-base, in [0,32)
    pd[m] = (dr & 7) >> 1;
    eyem[m] = ((dr >> 3) == q) ? ((dr & 1) ? 0x10000u : 1u) : 0u;
  }

  union { h8 s; int i[4]; } onef;
  {
    int v = (r0 == 0) ? 0x3C003C00 : 0;          // f16 1.0 pair
    onef.i[0]=v; onef.i[1]=v; onef.i[2]=v; onef.i[3]=v;
  }

  f32x4 acc[2][4];
  f32x4 accz[2];
  #pragma unroll
  for (int m = 0; m < 2; ++m){
    accz[m] = (f32x4){0.f,0.f,0.f,0.f};
    #pragma unroll
    for (int d = 0; d < 4; ++d)
      acc[m][d] = (f32x4){0.f,0.f,0.f,0.f};
  }

#define STAGE(bufoff, t) do { \
    const _Float16* _g = gp + (t)*128; \
    _Pragma("unroll") \
    for (int _s = 0; _s < 4; ++_s) \
      __builtin_amdgcn_global_load_lds( \
        (const __attribute__((address_space(1))) void*)(_g + _s*32), \
        (__attribute__((address_space(3))) void*)(lb + (bufoff) + _s*4096), 16, 0, 0); \
  } while(0)

#define LD_ADJ(dst, off) do { \
    dst[0][0] = *(const i32x4*)(ap0 + (off)); \
    dst[0][1] = *(const i32x4*)(ap0 + (off) + 4); \
    dst[1][0] = *(const i32x4*)(ap1 + (off)); \
    dst[1][1] = *(const i32x4*)(ap1 + (off) + 4); \
  } while(0)

  i32x4 ac[2][2], an[2][2];                      // adj current / next subtile
  LD_ADJ(ac, 0);
  STAGE(0, 0);
  __syncthreads();                               // tile 0 resident in buf0

  for (int t = 0; t < 16; ++t){
    const int bo = (t & 1) ? 16384 : 0;
    const int bn = bo ^ 16384;
    const int tn = (t + 1) & 15;                 // tail wrap harmless
    STAGE(bn, tn);                               // async: next ht tile -> other buffer

    #pragma unroll
    for (int ss = 0; ss < 4; ++ss){
      // prefetch next subtile's adj (cross-tile at ss==3)
      const int noff = (ss < 3) ? (t*128 + (ss+1)*32) : (tn*128);
      LD_ADJ(an, noff);

      i32x4 er4  = *(const i32x4*)(erq  + t*128 + ss*32);
      i32x4 er24 = *(const i32x4*)(er2q + t*128 + ss*32);

      h8 hf[4];
      #pragma unroll
      for (int d = 0; d < 4; ++d)
        hf[d] = *(const h8*)(frp + bo + ss*4096 + d*1024);   // ds_read_b128

      #pragma unroll
      for (int m = 0; m < 2; ++m){
        const bool dg = db[m] && (t == td[m]) && (ss == sd[m]);
        unsigned fu[4];
        #pragma unroll
        for (int p = 0; p < 4; ++p){
          const int a0 = ac[m][p >> 1][(p & 1)*2];
          const int a1 = ac[m][p >> 1][(p & 1)*2 + 1];
          unsigned t32 = (unsigned)a0 | ((unsigned)a1 << 16);
          if (dg) t32 |= (p == pd[m]) ? eyem[m] : 0u;        // +eye (rare subtile)
          const unsigned msk = t32 * 0xFFFFu;                // {0,1}x2 -> f16 masks
          h2 w2 = __builtin_elementwise_max(elh[m]  * u2h2((unsigned)er4[p]),
                                            el2h[m] * u2h2((unsigned)er24[p]));
          fu[p] = h22u(w2) & msk;
        }
        union { h8 s; unsigned u[4]; } fa;
        fa.u[0]=fu[0]; fa.u[1]=fu[1]; fa.u[2]=fu[2]; fa.u[3]=fu[3];
        #pragma unroll
        for (int d = 0; d < 4; ++d)
          acc[m][d] = __builtin_amdgcn_mfma_f32_16x16x32_f16(fa.s, hf[d], acc[m][d], 0, 0, 0);
        accz[m] = __builtin_amdgcn_mfma_f32_16x16x32_f16(fa.s, onef.s, accz[m], 0, 0, 0);
      }

      #pragma unroll
      for (int m = 0; m < 2; ++m){
        ac[m][0] = an[m][0]; ac[m][1] = an[m][1];
      }
    }

    __syncthreads();                             // next ht tile staged; buf free
  }

  // z partials: col 0 of accz -> lanes with r0==0, row = q*4+reg
  if (r0 == 0){
    #pragma unroll
    for (int m = 0; m < 2; ++m)
      #pragma unroll
      for (int reg = 0; reg < 4; ++reg)
        zpart[(jq*4 + h)*N + ib + m*16 + q*4 + reg] = accz[m][reg];
  }

  // numerator partials: C layout col=r0, row=q*4+reg
  float* pp = part + (size_t)jq*N*HD + h*64 + r0;
  #pragma unroll
  for (int m = 0; m < 2; ++m)
    #pragma unroll
    for (int d = 0; d < 4; ++d)
      #pragma unroll
      for (int reg = 0; reg < 4; ++reg)
        pp[(size_t)(ib + m*16 + q*4 + reg)*HD + d*16] = acc[m][d][reg];
#undef STAGE
#undef LD_ADJ
}

// ---------------- K3: combine 4 j-quarter partials, divide, write out --------------
__global__ void k_out(const float* __restrict__ part, const float* __restrict__ zpart,
                      float* __restrict__ out)
{
  const int t4 = (blockIdx.x*256 + threadIdx.x) * 4;   // 4 consecutive c (same head)
  const int i = t4 >> 8;
  const int h = (t4 & 255) >> 6;
  f32x4 a = *(const f32x4*)(part + t4);
  f32x4 bq = *(const f32x4*)(part + (size_t)N*HD + t4);
  f32x4 c = *(const f32x4*)(part + 2*(size_t)N*HD + t4);
  f32x4 d = *(const f32x4*)(part + 3*(size_t)N*HD + t4);
  float zz = zpart[h*N + i] + zpart[(4 + h)*N + i] + zpart[(8 + h)*N + i] + zpart[(12 + h)*N + i];
  f32x4 s = (a + bq + c + d) / zz;
  *(f32x4*)(out + t4) = s;
}

extern "C" void kernel_launch(void* const* d_in, const int* in_sizes, int n_in,
                              void* d_out, int out_size, void* d_ws, size_t ws_size,
                              hipStream_t stream) {
  const float* x   = (const float*)d_in[0];
  const int*   adj = (const int*)d_in[1];
  const float* W   = (const float*)d_in[2];
  const float* a_l = (const float*)d_in[3];
  const float* a_r = (const float*)d_in[4];
  float* out = (float*)d_out;

  char* ws = (char*)d_ws;
  __hip_bfloat16* Wt = (__hip_bfloat16*)ws;                     // 128 KB
  _Float16* ht   = (_Float16*)(ws + 131072);                    // 4 MB
  float*    El   = (float*)   (ws + 4325376);                   // 128 KB
  float*    El2  = (float*)   (ws + 4456448);                   // 128 KB
  _Float16* Erh  = (_Float16*)(ws + 4587520);                   // 64 KB
  _Float16* Er2h = (_Float16*)(ws + 4653056);                   // 64 KB
  float*    part = (float*)   (ws + 4718592);                   // 32 MB
  float*    zpart= (float*)   (ws + 38273024);                  // 512 KB

  k_wt  <<<dim3(16,16), dim3(16,16), 0, stream>>>(W, Wt);
  k_h   <<<256, 256, 0, stream>>>(x, Wt, a_l, a_r, ht, El, El2, Erh, Er2h);
  k_attn<<<1024, 256, 0, stream>>>(adj, ht, El, El2, Erh, Er2h, part, zpart);
  k_out <<<N*HD/1024, 256, 0, stream>>>(part, zpart, out);
}